// Round 5
// baseline (100.216 us; speedup 1.0000x reference)
//
#include <hip/hip_runtime.h>

#define BB 8
#define CC 512
#define NH 8
#define HD 64
#define HH 96
#define WW 96
#define AMP 3
#define KS 7
#define TH 16
#define TW 32
#define NTHR 256
#define HALO_H (TH + 2*AMP)          // 22
#define NGRP 10                      // 10 x 4 cols = 40 staged cols (x0 = w0-4)
#define LDSW 42                      // EVEN dword stride -> b64-aligned rows, bank-balanced
#define NPAIR 2                      // d-pairs per chunk (= 4 planes)
#define NCHUNK 16                    // 64 planes / 4
#define PLANE (HH * WW)              // 9216
#define NPLANE (NH * PLANE)          // 73728
#define NTOT (BB * CC * PLANE)
#define TASKS (NPAIR * HALO_H * NGRP) // 440
#define MAXS 2
#define LKHALF (NPAIR * HALO_H * LDSW) // 1848 h2 per buffer (even -> b64 ok both bufs)

typedef decltype(__builtin_amdgcn_cvt_pkrtz(0.f, 0.f)) h2;
typedef float f4 __attribute__((ext_vector_type(4)));

__device__ __forceinline__ float dot2f(h2 a, h2 b, float c) {
#if __has_builtin(__builtin_amdgcn_fdot2)
    return __builtin_amdgcn_fdot2(a, b, c, false);
#else
    return c + (float)a[0] * (float)b[0] + (float)a[1] * (float)b[1];
#endif
}

__device__ __forceinline__ void barrier_nb() {
    // lgkmcnt(0) only: LDS writes visible; global loads stay in flight (no vmcnt drain)
    asm volatile("s_waitcnt lgkmcnt(0)" ::: "memory");
    __builtin_amdgcn_s_barrier();
    asm volatile("" ::: "memory");
}

__global__ __launch_bounds__(NTHR)
void mov_kernel(const float* __restrict__ q, const float* __restrict__ k,
                float* __restrict__ out) {
    const int tid = threadIdx.x;
    const int tx  = tid & 15;          // 16 pixel-pairs wide
    const int ty  = tid >> 4;          // 16 rows
    // XCD-aware decode: all 18 tiles of one (b, head) slice share one XCD (bid%8)
    const int bid  = blockIdx.x;       // 0..1151
    const int n    = bid & 7;
    const int t2   = bid >> 3;         // 0..143
    const int b    = t2 / 18;
    const int tile = t2 - b * 18;
    const int th_i = tile / 3;         // 0..5
    const int tw_i = tile - th_i * 3;  // 0..2
    const int h0 = th_i * TH, w0 = tw_i * TW;
    const int h = h0 + ty, w = w0 + 2 * tx;

    __shared__ h2 lk[2 * LKHALF];

    // ---- fixed staging task map (2 tasks/thread, branch-free hot loop) ----
    int s_gpo[MAXS], s_lo[MAXS];
    bool s_v[MAXS];
#pragma unroll
    for (int s = 0; s < MAXS; ++s) {
        int id = tid + s * NTHR;
        s_v[s] = (id < TASKS);
        int id2 = s_v[s] ? id : 0;
        int p   = id2 / (HALO_H * NGRP);
        int rem = id2 - p * (HALO_H * NGRP);
        int r   = rem / NGRP;
        int g   = rem - r * NGRP;
        int y   = min(max(h0 + r - AMP, 0), HH - 1);   // clamped row; masked later
        s_gpo[s] = 2 * p * NPLANE + y * WW + (w0 - 4 + 4 * g);
        s_lo[s]  = (p * HALO_H + r) * LDSW + 4 * g;
    }

    const int kbase = (b * CC + n) * PLANE;
    const int qoff  = kbase + h * WW + w;
    const float scale = 0.125f;

    float acc0[KS * KS], acc1[KS * KS];
#pragma unroll
    for (int o = 0; o < KS * KS; ++o) { acc0[o] = 0.f; acc1[o] = 0.f; }

    f4 ska[MAXS], skb[MAXS];     // staged k: plane 2p / 2p+1
    float2 qv[4];                // this chunk's 4 q planes (2 pixels each)

    auto LOADK = [&](int c) {
#pragma unroll
        for (int s = 0; s < MAXS; ++s) {
            if (s_v[s]) {
                int base = kbase + c * 4 * NPLANE + s_gpo[s];
                int iA = min(max(base, 0), NTOT - 4);
                int iB = min(max(base + NPLANE, 0), NTOT - 4);
                ska[s] = *(const f4*)(k + iA);
                skb[s] = *(const f4*)(k + iB);
            }
        }
    };
    auto LOADQ = [&](int c) {
#pragma unroll
        for (int d = 0; d < 4; ++d)
            qv[d] = *(const float2*)(q + qoff + (c * 4 + d) * NPLANE);
    };
    auto WRITEK = [&](int buf) {
#pragma unroll
        for (int s = 0; s < MAXS; ++s) {
            if (s_v[s]) {
                h2* dst = &lk[buf * LKHALF + s_lo[s]];
#pragma unroll
                for (int u = 0; u < 4; ++u)
                    dst[u] = __builtin_amdgcn_cvt_pkrtz(ska[s][u], skb[s][u]);
            }
        }
    };

    LOADK(0);
    LOADQ(0);
    for (int c = 0; c < NCHUNK; ++c) {
        const int buf = c & 1;
        WRITEK(buf);                       // waits vmcnt on this chunk's k loads
        if (c + 1 < NCHUNK) LOADK(c + 1);  // reuse regs; in flight across barrier
        h2 qq0[NPAIR], qq1[NPAIR];
#pragma unroll
        for (int p = 0; p < NPAIR; ++p) {  // pack q pairs (d-major)
            qq0[p] = __builtin_amdgcn_cvt_pkrtz(qv[2 * p].x * scale, qv[2 * p + 1].x * scale);
            qq1[p] = __builtin_amdgcn_cvt_pkrtz(qv[2 * p].y * scale, qv[2 * p + 1].y * scale);
        }
        if (c + 1 < NCHUNK) LOADQ(c + 1);
        barrier_nb();
        // ---- 49-offset dot accumulation via v_dot2 (2 planes / instr) ----
        // kv row read at EVEN dword base (2*tx): 5x ds_read_b64, bank-balanced.
        // px0 (w)   uses kv[j+1], px1 (w+1) uses kv[j+2].
#pragma unroll
        for (int p = 0; p < NPAIR; ++p) {
#pragma unroll
            for (int i = 0; i < KS; ++i) {
                const int rb = buf * LKHALF + (p * HALO_H + ty + i) * LDSW + 2 * tx;
                h2 kv[10];
#pragma unroll
                for (int t = 0; t < 10; ++t) kv[t] = lk[rb + t];
#pragma unroll
                for (int j = 0; j < KS; ++j) {
                    acc0[i * KS + j] = dot2f(qq0[p], kv[j + 1], acc0[i * KS + j]);
                    acc1[i * KS + j] = dot2f(qq1[p], kv[j + 2], acc1[i * KS + j]);
                }
            }
        }
        barrier_nb();   // readers done before next overwrite of this buffer
    }

    // ---- mask invalid offsets (reference: -1000 -> exp == 0) ----
#pragma unroll
    for (int i = 0; i < KS; ++i) {
        bool vi = ((unsigned)(h + i - AMP) < HH);
#pragma unroll
        for (int j = 0; j < KS; ++j) {
            bool v0 = vi && ((unsigned)(w + j - AMP) < WW);
            bool v1 = vi && ((unsigned)(w + 1 + j - AMP) < WW);
            if (!v0) acc0[i * KS + j] = -1e30f;
            if (!v1) acc1[i * KS + j] = -1e30f;
        }
    }

    // ---- softmax over 49 offsets + expectation of (di, dj) ----
    float m0 = -1e30f, m1 = -1e30f;
#pragma unroll
    for (int o = 0; o < KS * KS; ++o) {
        m0 = fmaxf(m0, acc0[o]);
        m1 = fmaxf(m1, acc1[o]);
    }
    float l0 = 0.f, di0 = 0.f, dj0 = 0.f;
    float l1 = 0.f, di1 = 0.f, dj1 = 0.f;
#pragma unroll
    for (int i = 0; i < KS; ++i) {
#pragma unroll
        for (int j = 0; j < KS; ++j) {
            float e0 = __expf(acc0[i * KS + j] - m0);
            float e1 = __expf(acc1[i * KS + j] - m1);
            l0 += e0; l1 += e1;
            di0 += e0 * (float)(i - AMP);
            di1 += e1 * (float)(i - AMP);
            dj0 += e0 * (float)(j - AMP);
            dj1 += e1 * (float)(j - AMP);
        }
    }
    float inv0 = 1.0f / (l0 * (float)NH);
    float inv1 = 1.0f / (l1 * (float)NH);

    float* o0 = out + ((size_t)b * 2 + 0) * PLANE + h * WW + w;
    float* o1 = out + ((size_t)b * 2 + 1) * PLANE + h * WW + w;
    atomicAdd(o0,     di0 * inv0);
    atomicAdd(o0 + 1, di1 * inv1);
    atomicAdd(o1,     dj0 * inv0);
    atomicAdd(o1 + 1, dj1 * inv1);
}

extern "C" void kernel_launch(void* const* d_in, const int* in_sizes, int n_in,
                              void* d_out, int out_size, void* d_ws, size_t ws_size,
                              hipStream_t stream) {
    const float* q = (const float*)d_in[0];
    const float* k = (const float*)d_in[1];
    float* out = (float*)d_out;

    hipMemsetAsync(out, 0, (size_t)out_size * sizeof(float), stream);

    dim3 grid(BB * NH * (HH / TH) * (WW / TW));   // 1152, XCD-decoded in-kernel
    dim3 block(NTHR);
    hipLaunchKernelGGL(mov_kernel, grid, block, 0, stream, q, k, out);
}

// Round 6
// 92.604 us; speedup vs baseline: 1.0822x; 1.0822x over previous
//
#include <hip/hip_runtime.h>

#define BB 8
#define CC 512
#define NH 8
#define HD 64
#define HH 96
#define WW 96
#define AMP 3
#define KS 7
#define TH 16
#define TW 32
#define NTHR 256
#define HALO_H (TH + 2*AMP)          // 22
#define NGRP 10                      // 10 x 4 cols = 40 staged cols (x0 = w0-4)
#define LDSW 41                      // ODD dword stride: proven ~conflict-free (r3)
#define NPAIR 2                      // d-pairs per chunk (= 4 planes)
#define NCHUNK 16                    // 64 planes / 4
#define PLANE (HH * WW)              // 9216
#define NPLANE (NH * PLANE)          // 73728
#define NTOT (BB * CC * PLANE)
#define TASKS (NPAIR * HALO_H * NGRP) // 440
#define MAXS 2
#define LKHALF (NPAIR * HALO_H * LDSW) // 1804 h2 per buffer

typedef decltype(__builtin_amdgcn_cvt_pkrtz(0.f, 0.f)) h2;
typedef float f4 __attribute__((ext_vector_type(4)));

// Force arch-VGPR accumulation: VOP3P v_dot2_f32_f16 cannot address AGPRs,
// and the "+v" register-class constraint forbids the allocator's
// accvgpr_read/write ping-pong that inflated VALU 3x in rounds 2-4.
__device__ __forceinline__ void dot2a(float& c, h2 a, h2 b) {
    asm("v_dot2_f32_f16 %0, %1, %2, %0" : "+v"(c) : "v"(a), "v"(b));
}

__device__ __forceinline__ void barrier_nb() {
    // lgkmcnt(0) only: LDS writes visible; global loads stay in flight (no vmcnt drain)
    asm volatile("s_waitcnt lgkmcnt(0)" ::: "memory");
    __builtin_amdgcn_s_barrier();
    asm volatile("" ::: "memory");
}

__global__ __launch_bounds__(NTHR, 2)   // 2 waves/EU min -> 256-VGPR budget, no AGPR games
void mov_kernel(const float* __restrict__ q, const float* __restrict__ k,
                float* __restrict__ out) {
    const int tid = threadIdx.x;
    const int tx  = tid & 15;          // 16 pixel-pairs wide
    const int ty  = tid >> 4;          // 16 rows
    // XCD-aware decode: all 18 tiles of one (b, head) slice share one XCD (bid%8)
    const int bid  = blockIdx.x;       // 0..1151
    const int n    = bid & 7;
    const int t2   = bid >> 3;         // 0..143
    const int b    = t2 / 18;
    const int tile = t2 - b * 18;
    const int th_i = tile / 3;         // 0..5
    const int tw_i = tile - th_i * 3;  // 0..2
    const int h0 = th_i * TH, w0 = tw_i * TW;
    const int h = h0 + ty, w = w0 + 2 * tx;

    __shared__ h2 lk[2 * LKHALF];

    // ---- fixed staging task map (2 tasks/thread, branch-free hot loop) ----
    int s_gpo[MAXS], s_lo[MAXS];
    bool s_v[MAXS];
#pragma unroll
    for (int s = 0; s < MAXS; ++s) {
        int id = tid + s * NTHR;
        s_v[s] = (id < TASKS);
        int id2 = s_v[s] ? id : 0;
        int p   = id2 / (HALO_H * NGRP);
        int rem = id2 - p * (HALO_H * NGRP);
        int r   = rem / NGRP;
        int g   = rem - r * NGRP;
        int y   = min(max(h0 + r - AMP, 0), HH - 1);   // clamped row; masked later
        s_gpo[s] = 2 * p * NPLANE + y * WW + (w0 - 4 + 4 * g);
        s_lo[s]  = (p * HALO_H + r) * LDSW + 4 * g;
    }

    const int kbase = (b * CC + n) * PLANE;
    const int qoff  = kbase + h * WW + w;
    const float scale = 0.125f;

    float acc0[KS * KS], acc1[KS * KS];
#pragma unroll
    for (int o = 0; o < KS * KS; ++o) { acc0[o] = 0.f; acc1[o] = 0.f; }

    f4 ska[MAXS], skb[MAXS];     // staged k: plane 2p / 2p+1
    float2 qv[4];                // this chunk's 4 q planes (2 pixels each)

    auto LOADK = [&](int c) {
#pragma unroll
        for (int s = 0; s < MAXS; ++s) {
            if (s_v[s]) {
                int base = kbase + c * 4 * NPLANE + s_gpo[s];
                int iA = min(max(base, 0), NTOT - 4);
                int iB = min(max(base + NPLANE, 0), NTOT - 4);
                ska[s] = *(const f4*)(k + iA);
                skb[s] = *(const f4*)(k + iB);
            }
        }
    };
    auto LOADQ = [&](int c) {
#pragma unroll
        for (int d = 0; d < 4; ++d)
            qv[d] = *(const float2*)(q + qoff + (c * 4 + d) * NPLANE);
    };
    auto WRITEK = [&](int buf) {
#pragma unroll
        for (int s = 0; s < MAXS; ++s) {
            if (s_v[s]) {
                h2* dst = &lk[buf * LKHALF + s_lo[s]];
#pragma unroll
                for (int u = 0; u < 4; ++u)
                    dst[u] = __builtin_amdgcn_cvt_pkrtz(ska[s][u], skb[s][u]);
            }
        }
    };

    LOADK(0);
    LOADQ(0);
    for (int c = 0; c < NCHUNK; ++c) {
        const int buf = c & 1;
        WRITEK(buf);                       // waits vmcnt on this chunk's k loads
        if (c + 1 < NCHUNK) LOADK(c + 1);  // reuse regs; in flight across barrier
        h2 qq0[NPAIR], qq1[NPAIR];
#pragma unroll
        for (int p = 0; p < NPAIR; ++p) {  // pack q pairs (d-major)
            qq0[p] = __builtin_amdgcn_cvt_pkrtz(qv[2 * p].x * scale, qv[2 * p + 1].x * scale);
            qq1[p] = __builtin_amdgcn_cvt_pkrtz(qv[2 * p].y * scale, qv[2 * p + 1].y * scale);
        }
        if (c + 1 < NCHUNK) LOADQ(c + 1);
        barrier_nb();
        // ---- 49-offset dot accumulation via v_dot2 (2 planes / instr) ----
#pragma unroll
        for (int p = 0; p < NPAIR; ++p) {
#pragma unroll
            for (int i = 0; i < KS; ++i) {
                const int rb = buf * LKHALF + (p * HALO_H + ty + i) * LDSW + 2 * tx + 1;
                h2 kv[8];
#pragma unroll
                for (int t = 0; t < 8; ++t) kv[t] = lk[rb + t];
#pragma unroll
                for (int j = 0; j < KS; ++j) {
                    dot2a(acc0[i * KS + j], qq0[p], kv[j]);
                    dot2a(acc1[i * KS + j], qq1[p], kv[j + 1]);
                }
            }
        }
        barrier_nb();   // readers done before next overwrite of this buffer
    }

    // ---- mask invalid offsets (reference: -1000 -> exp == 0) ----
#pragma unroll
    for (int i = 0; i < KS; ++i) {
        bool vi = ((unsigned)(h + i - AMP) < HH);
#pragma unroll
        for (int j = 0; j < KS; ++j) {
            bool v0 = vi && ((unsigned)(w + j - AMP) < WW);
            bool v1 = vi && ((unsigned)(w + 1 + j - AMP) < WW);
            if (!v0) acc0[i * KS + j] = -1e30f;
            if (!v1) acc1[i * KS + j] = -1e30f;
        }
    }

    // ---- softmax over 49 offsets + expectation of (di, dj) ----
    float m0 = -1e30f, m1 = -1e30f;
#pragma unroll
    for (int o = 0; o < KS * KS; ++o) {
        m0 = fmaxf(m0, acc0[o]);
        m1 = fmaxf(m1, acc1[o]);
    }
    float l0 = 0.f, di0 = 0.f, dj0 = 0.f;
    float l1 = 0.f, di1 = 0.f, dj1 = 0.f;
#pragma unroll
    for (int i = 0; i < KS; ++i) {
#pragma unroll
        for (int j = 0; j < KS; ++j) {
            float e0 = __expf(acc0[i * KS + j] - m0);
            float e1 = __expf(acc1[i * KS + j] - m1);
            l0 += e0; l1 += e1;
            di0 += e0 * (float)(i - AMP);
            di1 += e1 * (float)(i - AMP);
            dj0 += e0 * (float)(j - AMP);
            dj1 += e1 * (float)(j - AMP);
        }
    }
    float inv0 = 1.0f / (l0 * (float)NH);
    float inv1 = 1.0f / (l1 * (float)NH);

    float* o0 = out + ((size_t)b * 2 + 0) * PLANE + h * WW + w;
    float* o1 = out + ((size_t)b * 2 + 1) * PLANE + h * WW + w;
    atomicAdd(o0,     di0 * inv0);
    atomicAdd(o0 + 1, di1 * inv1);
    atomicAdd(o1,     dj0 * inv0);
    atomicAdd(o1 + 1, dj1 * inv1);
}

extern "C" void kernel_launch(void* const* d_in, const int* in_sizes, int n_in,
                              void* d_out, int out_size, void* d_ws, size_t ws_size,
                              hipStream_t stream) {
    const float* q = (const float*)d_in[0];
    const float* k = (const float*)d_in[1];
    float* out = (float*)d_out;

    hipMemsetAsync(out, 0, (size_t)out_size * sizeof(float), stream);

    dim3 grid(BB * NH * (HH / TH) * (WW / TW));   // 1152, XCD-decoded in-kernel
    dim3 block(NTHR);
    hipLaunchKernelGGL(mov_kernel, grid, block, 0, stream, q, k, out);
}

// Round 7
// 85.876 us; speedup vs baseline: 1.1670x; 1.0783x over previous
//
#include <hip/hip_runtime.h>

#define BB 8
#define CC 512
#define NH 8
#define HD 64
#define HH 96
#define WW 96
#define AMP 3
#define KS 7
#define TH 16
#define TW 32
#define NTHR 256
#define HALO_H (TH + 2*AMP)      // 22
#define NCOL 40                  // staged cols: w0-4 .. w0+35
#define ROWH2 (NCOL * 2)         // 80 h2 per row ([col][pair] interleaved)
#define LKSZ (HALO_H * ROWH2)    // 1760 h2 per buffer
#define NCHUNK 16                // 64 d / 4 per chunk
#define PLANE (HH * WW)          // 9216
#define NPLANE (NH * PLANE)      // 73728
#define NTOT (BB * CC * PLANE)
#define TASKS (HALO_H * 10)      // 220 staging tasks (4 cols x 4 planes each)

typedef decltype(__builtin_amdgcn_cvt_pkrtz(0.f, 0.f)) h2;
typedef float f4 __attribute__((ext_vector_type(4)));
typedef _Float16 h8 __attribute__((ext_vector_type(8)));   // 16B LDS vector

union H8U { h8 v; h2 h[4]; };

// VOP3P dot2 (cannot address AGPRs -> keeps accumulate on arch VGPRs at use)
__device__ __forceinline__ void dot2a(float& c, h2 a, h2 b) {
    asm("v_dot2_f32_f16 %0, %1, %2, %0" : "+v"(c) : "v"(a), "v"(b));
}

__device__ __forceinline__ void barrier_nb() {
    // lgkmcnt(0) only: LDS writes visible; global loads stay in flight
    asm volatile("s_waitcnt lgkmcnt(0)" ::: "memory");
    __builtin_amdgcn_s_barrier();
    asm volatile("" ::: "memory");
}

__global__ __launch_bounds__(NTHR)
void mov_kernel(const float* __restrict__ q, const float* __restrict__ k,
                float* __restrict__ out) {
    const int tid = threadIdx.x;
    const int tx  = tid & 15;          // 16 pixel-pairs wide
    const int ty  = tid >> 4;          // 16 rows
    // XCD-aware decode: all 18 tiles of one (b, head) slice share one XCD
    const int bid  = blockIdx.x;       // 0..1151
    const int n    = bid & 7;
    const int t2   = bid >> 3;
    const int b    = t2 / 18;
    const int tile = t2 - b * 18;
    const int th_i = tile / 3;
    const int tw_i = tile - th_i * 3;
    const int h0 = th_i * TH, w0 = tw_i * TW;
    const int h = h0 + ty, w = w0 + 2 * tx;

    __shared__ h2 lk[2 * LKSZ];

    // ---- staging task: 1 per thread (tid < 220): row r, col-group g ----
    const bool sv = (tid < TASKS);
    const int r_  = sv ? tid / 10 : 0;
    const int g_  = sv ? tid - r_ * 10 : 0;
    const int y_  = min(max(h0 + r_ - AMP, 0), HH - 1);
    const int sgo = y_ * WW + (w0 - 4 + 4 * g_);       // global offset in plane
    const int slo = r_ * ROWH2 + 8 * g_;               // LDS h2 offset

    const int kbase = (b * CC + n) * PLANE;
    const int qoff  = kbase + h * WW + w;
    const float scale = 0.125f;

    float acc0[KS * KS], acc1[KS * KS];
#pragma unroll
    for (int o = 0; o < KS * KS; ++o) { acc0[o] = 0.f; acc1[o] = 0.f; }

    f4 ka, kb, kc, kd;     // 4 planes of this task's 4 cols
    float2 qv[4];          // this chunk's 4 q planes (2 pixels each)

    auto LOADK = [&](int c) {
        if (sv) {
            int base = kbase + c * 4 * NPLANE + sgo;
            int i0 = min(max(base,              0), NTOT - 4);
            int i1 = min(max(base +     NPLANE, 0), NTOT - 4);
            int i2 = min(max(base + 2 * NPLANE, 0), NTOT - 4);
            int i3 = min(max(base + 3 * NPLANE, 0), NTOT - 4);
            ka = *(const f4*)(k + i0);
            kb = *(const f4*)(k + i1);
            kc = *(const f4*)(k + i2);
            kd = *(const f4*)(k + i3);
        }
    };
    auto LOADQ = [&](int c) {
#pragma unroll
        for (int d = 0; d < 4; ++d)
            qv[d] = *(const float2*)(q + qoff + (c * 4 + d) * NPLANE);
    };
    auto WRITEK = [&](int buf) {
        if (sv) {
            H8U u0, u1;
            u0.h[0] = __builtin_amdgcn_cvt_pkrtz(ka.x, kb.x);  // col0 pair0
            u0.h[1] = __builtin_amdgcn_cvt_pkrtz(kc.x, kd.x);  // col0 pair1
            u0.h[2] = __builtin_amdgcn_cvt_pkrtz(ka.y, kb.y);
            u0.h[3] = __builtin_amdgcn_cvt_pkrtz(kc.y, kd.y);
            u1.h[0] = __builtin_amdgcn_cvt_pkrtz(ka.z, kb.z);
            u1.h[1] = __builtin_amdgcn_cvt_pkrtz(kc.z, kd.z);
            u1.h[2] = __builtin_amdgcn_cvt_pkrtz(ka.w, kb.w);
            u1.h[3] = __builtin_amdgcn_cvt_pkrtz(kc.w, kd.w);
            h2* dst = &lk[buf * LKSZ + slo];
            *(h8*)(dst)     = u0.v;
            *(h8*)(dst + 4) = u1.v;
        }
    };

    LOADK(0);
    LOADQ(0);
    for (int c = 0; c < NCHUNK; ++c) {
        const int buf = c & 1;
        WRITEK(buf);                       // vmcnt-waits this chunk's k loads
        if (c + 1 < NCHUNK) LOADK(c + 1);
        // pack q: A = planes(d0,d1), B = planes(d2,d3); 0 = px0, 1 = px1
        h2 qA0 = __builtin_amdgcn_cvt_pkrtz(qv[0].x * scale, qv[1].x * scale);
        h2 qB0 = __builtin_amdgcn_cvt_pkrtz(qv[2].x * scale, qv[3].x * scale);
        h2 qA1 = __builtin_amdgcn_cvt_pkrtz(qv[0].y * scale, qv[1].y * scale);
        h2 qB1 = __builtin_amdgcn_cvt_pkrtz(qv[2].y * scale, qv[3].y * scale);
        if (c + 1 < NCHUNK) LOADQ(c + 1);
        barrier_nb();                      // buf fully written, then read
        // ---- per halo row i: 5x ds_read_b128 -> 28 dot2 ----
#pragma unroll
        for (int i = 0; i < KS; ++i) {
            const h2* row = &lk[buf * LKSZ + (ty + i) * ROWH2 + 4 * tx];
            h2 kvA[10], kvB[10];
#pragma unroll
            for (int m = 0; m < 5; ++m) {
                H8U u; u.v = *(const h8*)(row + 4 * m);
                kvA[2 * m]     = u.h[0];   // col 2m,   pair0
                kvB[2 * m]     = u.h[1];   // col 2m,   pair1
                kvA[2 * m + 1] = u.h[2];
                kvB[2 * m + 1] = u.h[3];
            }
#pragma unroll
            for (int j = 0; j < KS; ++j) {
                dot2a(acc0[i * KS + j], qA0, kvA[j + 1]);
                dot2a(acc0[i * KS + j], qB0, kvB[j + 1]);
                dot2a(acc1[i * KS + j], qA1, kvA[j + 2]);
                dot2a(acc1[i * KS + j], qB1, kvB[j + 2]);
            }
        }
        // no trailing barrier: buf is next overwritten at c+2, which is
        // already ordered after barrier(c+1) -> double buffer is race-free
    }

    // ---- mask invalid offsets (reference: -1000 -> exp == 0) ----
#pragma unroll
    for (int i = 0; i < KS; ++i) {
        bool vi = ((unsigned)(h + i - AMP) < HH);
#pragma unroll
        for (int j = 0; j < KS; ++j) {
            bool v0 = vi && ((unsigned)(w + j - AMP) < WW);
            bool v1 = vi && ((unsigned)(w + 1 + j - AMP) < WW);
            if (!v0) acc0[i * KS + j] = -1e30f;
            if (!v1) acc1[i * KS + j] = -1e30f;
        }
    }

    // ---- softmax over 49 offsets + expectation of (di, dj) ----
    float m0 = -1e30f, m1 = -1e30f;
#pragma unroll
    for (int o = 0; o < KS * KS; ++o) {
        m0 = fmaxf(m0, acc0[o]);
        m1 = fmaxf(m1, acc1[o]);
    }
    float l0 = 0.f, di0 = 0.f, dj0 = 0.f;
    float l1 = 0.f, di1 = 0.f, dj1 = 0.f;
#pragma unroll
    for (int i = 0; i < KS; ++i) {
#pragma unroll
        for (int j = 0; j < KS; ++j) {
            float e0 = __expf(acc0[i * KS + j] - m0);
            float e1 = __expf(acc1[i * KS + j] - m1);
            l0 += e0; l1 += e1;
            di0 += e0 * (float)(i - AMP);
            di1 += e1 * (float)(i - AMP);
            dj0 += e0 * (float)(j - AMP);
            dj1 += e1 * (float)(j - AMP);
        }
    }
    float inv0 = 1.0f / (l0 * (float)NH);
    float inv1 = 1.0f / (l1 * (float)NH);

    float* o0 = out + ((size_t)b * 2 + 0) * PLANE + h * WW + w;
    float* o1 = out + ((size_t)b * 2 + 1) * PLANE + h * WW + w;
    atomicAdd(o0,     di0 * inv0);
    atomicAdd(o0 + 1, di1 * inv1);
    atomicAdd(o1,     dj0 * inv0);
    atomicAdd(o1 + 1, dj1 * inv1);
}

extern "C" void kernel_launch(void* const* d_in, const int* in_sizes, int n_in,
                              void* d_out, int out_size, void* d_ws, size_t ws_size,
                              hipStream_t stream) {
    const float* q = (const float*)d_in[0];
    const float* k = (const float*)d_in[1];
    float* out = (float*)d_out;

    hipMemsetAsync(out, 0, (size_t)out_size * sizeof(float), stream);

    dim3 grid(BB * NH * (HH / TH) * (WW / TW));   // 1152
    dim3 block(NTHR);
    hipLaunchKernelGGL(mov_kernel, grid, block, 0, stream, q, k, out);
}